// Round 2
// baseline (2683.488 us; speedup 1.0000x reference)
//
#include <hip/hip_runtime.h>
#include <math.h>

#define BB 128
#define CC 512
#define HW 1024
#define EE 16
#define KK 2
#define INV_NOISE_STD 16.0f
#define EPSV 1e-8f
#define NBLK ((BB * CC) / 8)   // 8192 blocks x 512 threads = 65536 waves = B*C

__device__ __forceinline__ float wave_sum(float v) {
    #pragma unroll
    for (int off = 32; off > 0; off >>= 1) v += __shfl_down(v, off, 64);
    return v;
}

// One fused kernel. Phase 1 (all blocks): each wave reduces one (b,c) plane of
// 1024 floats -> pooled[b*C+c]. Release fence + counter; last block computes
// logits from L2-hot pooled, then all softmax/top-2/loss statistics.
__global__ void __launch_bounds__(512) fused_kernel(
    const float* __restrict__ x, const float* __restrict__ Wg,
    const float* __restrict__ complexity, const float* __restrict__ noise,
    float* __restrict__ out, float* __restrict__ pooled,
    unsigned int* __restrict__ counter)
{
    __shared__ float lgs[BB * EE];     // 8 KB: logits
    __shared__ float imp[EE], psum[EE];
    __shared__ int is_last;

    int t = threadIdx.x;
    int lane = t & 63;
    int wave = blockIdx.x * 8 + (t >> 6);        // global (b*C+c)

    // ---- Phase 1: pooled mean over HW=1024 contiguous floats, one wave each
    const float4* p = (const float4*)(x + (size_t)wave * HW);
    float s = 0.0f;
    #pragma unroll
    for (int j = 0; j < 4; ++j) {
        float4 v = p[lane + 64 * j];
        s += (v.x + v.y) + (v.z + v.w);
    }
    s = wave_sum(s);
    if (lane == 0) pooled[wave] = s * (1.0f / 1024.0f);

    // ---- release: make pooled stores visible device-wide, then count in
    __threadfence();
    __syncthreads();
    if (t == 0) {
        unsigned int old = atomicAdd(counter, 1u);
        is_last = (old == NBLK - 1) ? 1 : 0;
    }
    __syncthreads();
    if (!is_last) return;
    __threadfence();   // acquire side

    // ---- Phase 2 (last block only): logits[b,e] = dot(pooled[b,:], Wg[e,:])
    {
        int e = t & 15, bs = t >> 4;             // bs in 0..31
        for (int b = bs; b < BB; b += 32) {
            const float4* pr = (const float4*)(pooled + b * CC);
            const float4* wr = (const float4*)(Wg + e * CC);
            float acc = 0.0f;
            #pragma unroll 4
            for (int c = 0; c < CC / 4; ++c) {
                float4 a = pr[c], w = wr[c];
                acc += a.x * w.x + a.y * w.y + a.z * w.z + a.w * w.w;
            }
            lgs[b * EE + e] = acc;
        }
    }
    if (t < EE) { imp[t] = 0.0f; psum[t] = 0.0f; }
    __syncthreads();

    // ---- Phase 3: per-row statistics (threads 0..127 = batch rows)
    if (t < BB) {
        int b = t;
        float lg[EE], nlg[EE];
        #pragma unroll
        for (int e = 0; e < EE; ++e) lg[e] = lgs[b * EE + e];
        #pragma unroll
        for (int e = 0; e < EE; ++e) nlg[e] = lg[e] + noise[b * EE + e];

        // softmax(logits) -> importance accumulation
        float mx = lg[0];
        #pragma unroll
        for (int e = 1; e < EE; ++e) mx = fmaxf(mx, lg[e]);
        float sm[EE]; float se = 0.0f;
        #pragma unroll
        for (int e = 0; e < EE; ++e) { sm[e] = expf(lg[e] - mx); se += sm[e]; }
        float inv_se = 1.0f / se;
        #pragma unroll
        for (int e = 0; e < EE; ++e) {
            float ws = wave_sum(sm[e] * inv_se);
            if (lane == 0) atomicAdd(&imp[e], ws);
        }

        // softmax(noisy) -> gating scores; top-2 with lowest-index tie-break
        float mxn = nlg[0];
        #pragma unroll
        for (int e = 1; e < EE; ++e) mxn = fmaxf(mxn, nlg[e]);
        float gsc[EE]; float sen = 0.0f;
        #pragma unroll
        for (int e = 0; e < EE; ++e) { gsc[e] = expf(nlg[e] - mxn); sen += gsc[e]; }
        float inv_sen = 1.0f / sen;
        #pragma unroll
        for (int e = 0; e < EE; ++e) gsc[e] *= inv_sen;

        int i1 = 0;
        #pragma unroll
        for (int e = 1; e < EE; ++e) if (nlg[e] > nlg[i1]) i1 = e;
        int i2 = (i1 == 0) ? 1 : 0;
        #pragma unroll
        for (int e = 0; e < EE; ++e) if (e != i1 && e != i2 && nlg[e] > nlg[i2]) i2 = e;
        float thr = nlg[i2];
        float v1 = gsc[i1], v2 = gsc[i2];

        // p[e] = P(noisy logit beats threshold) = 0.5*erfc((thr-lg)*16/sqrt2)
        #pragma unroll
        for (int e = 0; e < EE; ++e) {
            float z = (thr - lg[e]) * INV_NOISE_STD;
            float pv = 0.5f * erfcf(z * 0.70710678118654752f);
            float ws = wave_sum(pv);
            if (lane == 0) atomicAdd(&psum[e], ws);
        }

        // outputs: gates[B*E] | idx[B*K] | vals[B*K] | aux[1]
        #pragma unroll
        for (int e = 0; e < EE; ++e)
            out[b * EE + e] = (e == i1) ? v1 : ((e == i2) ? v2 : 0.0f);
        out[BB * EE + b * KK + 0] = (float)i1;
        out[BB * EE + b * KK + 1] = (float)i2;
        out[BB * EE + BB * KK + b * KK + 0] = v1;
        out[BB * EE + BB * KK + b * KK + 1] = v2;
    }
    __syncthreads();

    if (t == 0) {
        float im[EE]; float mean1 = 0.0f;
        #pragma unroll
        for (int e = 0; e < EE; ++e) { im[e] = imp[e] * complexity[e]; mean1 += im[e]; }
        mean1 *= (1.0f / EE);
        float var1 = 0.0f;
        #pragma unroll
        for (int e = 0; e < EE; ++e) { float d = im[e] - mean1; var1 += d * d; }
        var1 *= (1.0f / (EE - 1));
        float li = var1 / ((mean1 + EPSV) * (mean1 + EPSV));

        float pm[EE]; float mean2 = 0.0f;
        #pragma unroll
        for (int e = 0; e < EE; ++e) { pm[e] = psum[e] * (1.0f / BB); mean2 += pm[e]; }
        mean2 *= (1.0f / EE);
        float var2 = 0.0f;
        #pragma unroll
        for (int e = 0; e < EE; ++e) { float d = pm[e] - mean2; var2 += d * d; }
        var2 *= (1.0f / (EE - 1));
        float ll = var2 / ((mean2 + EPSV) * (mean2 + EPSV));

        out[BB * EE + 2 * BB * KK] = 0.5f * li + 0.5f * ll;
    }
}

extern "C" void kernel_launch(void* const* d_in, const int* in_sizes, int n_in,
                              void* d_out, int out_size, void* d_ws, size_t ws_size,
                              hipStream_t stream) {
    const float* x     = (const float*)d_in[0];   // [128,512,32,32]
    const float* Wg    = (const float*)d_in[1];   // [16,512]
    const float* comp  = (const float*)d_in[2];   // [16]
    const float* noise = (const float*)d_in[3];   // [128,16]
    float* out = (float*)d_out;

    unsigned int* counter = (unsigned int*)d_ws;          // 4 B, zeroed below
    float* pooled = (float*)d_ws + 64;                    // 256 B offset, B*C floats

    hipMemsetAsync(d_ws, 0, 16, stream);                  // counter = 0 (d_ws is poisoned)
    fused_kernel<<<NBLK, 512, 0, stream>>>(x, Wg, comp, noise, out, pooled, counter);
}

// Round 3
// 509.828 us; speedup vs baseline: 5.2635x; 5.2635x over previous
//
#include <hip/hip_runtime.h>
#include <math.h>

#define BB 128
#define CC 512
#define HW 1024
#define EE 16
#define KK 2
#define INV_NOISE_STD 16.0f
#define EPSV 1e-8f

__device__ __forceinline__ float wave_sum(float v) {
    #pragma unroll
    for (int off = 32; off > 0; off >>= 1) v += __shfl_down(v, off, 64);
    return v;
}

// Kernel A: pooled[p] = mean over 1024 contiguous floats. One wave per (b,c).
// 8192 blocks x 512 threads = 65536 waves. Coalesced float4, 16 B/lane.
__global__ void __launch_bounds__(512) pool_kernel(const float* __restrict__ x,
                                                   float* __restrict__ pooled) {
    int wave = (blockIdx.x << 3) + (threadIdx.x >> 6);   // global (b*C+c)
    int lane = threadIdx.x & 63;
    const float4* p = (const float4*)(x + (size_t)wave * HW);
    float s = 0.0f;
    #pragma unroll
    for (int j = 0; j < 4; ++j) {
        float4 v = p[lane + 64 * j];
        s += (v.x + v.y) + (v.z + v.w);
    }
    s = wave_sum(s);
    if (lane == 0) pooled[wave] = s * (1.0f / 1024.0f);
}

// Kernel B: logits (from L2-hot pooled) + all statistics. ONE block, 512 threads.
__global__ void __launch_bounds__(512) tail_kernel(const float* __restrict__ pooled,
                                                   const float* __restrict__ Wg,
                                                   const float* __restrict__ complexity,
                                                   const float* __restrict__ noise,
                                                   float* __restrict__ out) {
    __shared__ float lgs[BB * EE];   // 8 KB logits
    __shared__ float imp[EE], psum[EE];
    int t = threadIdx.x;
    int lane = t & 63;

    // ---- logits[b,e] = dot(pooled[b,:], Wg[e,:]); 512 threads -> 4 dots each
    {
        int e = t & 15, bs = t >> 4;             // bs in 0..31
        for (int b = bs; b < BB; b += 32) {
            const float4* pr = (const float4*)(pooled + b * CC);
            const float4* wr = (const float4*)(Wg + e * CC);
            float acc = 0.0f;
            #pragma unroll 4
            for (int c = 0; c < CC / 4; ++c) {
                float4 a = pr[c], w = wr[c];
                acc += a.x * w.x + a.y * w.y + a.z * w.z + a.w * w.w;
            }
            lgs[b * EE + e] = acc;
        }
    }
    if (t < EE) { imp[t] = 0.0f; psum[t] = 0.0f; }
    __syncthreads();

    // ---- per-row statistics (threads 0..127 = batch rows)
    if (t < BB) {
        int b = t;
        float lg[EE], nlg[EE];
        #pragma unroll
        for (int e = 0; e < EE; ++e) lg[e] = lgs[b * EE + e];
        #pragma unroll
        for (int e = 0; e < EE; ++e) nlg[e] = lg[e] + noise[b * EE + e];

        // softmax(logits) -> importance accumulation
        float mx = lg[0];
        #pragma unroll
        for (int e = 1; e < EE; ++e) mx = fmaxf(mx, lg[e]);
        float sm[EE]; float se = 0.0f;
        #pragma unroll
        for (int e = 0; e < EE; ++e) { sm[e] = expf(lg[e] - mx); se += sm[e]; }
        float inv_se = 1.0f / se;
        #pragma unroll
        for (int e = 0; e < EE; ++e) {
            float ws = wave_sum(sm[e] * inv_se);
            if (lane == 0) atomicAdd(&imp[e], ws);
        }

        // softmax(noisy) -> gating scores; top-2, lowest-index tie-break
        float mxn = nlg[0];
        #pragma unroll
        for (int e = 1; e < EE; ++e) mxn = fmaxf(mxn, nlg[e]);
        float gsc[EE]; float sen = 0.0f;
        #pragma unroll
        for (int e = 0; e < EE; ++e) { gsc[e] = expf(nlg[e] - mxn); sen += gsc[e]; }
        float inv_sen = 1.0f / sen;
        #pragma unroll
        for (int e = 0; e < EE; ++e) gsc[e] *= inv_sen;

        int i1 = 0;
        #pragma unroll
        for (int e = 1; e < EE; ++e) if (nlg[e] > nlg[i1]) i1 = e;
        int i2 = (i1 == 0) ? 1 : 0;
        #pragma unroll
        for (int e = 0; e < EE; ++e) if (e != i1 && e != i2 && nlg[e] > nlg[i2]) i2 = e;
        float thr = nlg[i2];
        float v1 = gsc[i1], v2 = gsc[i2];

        // p[e] = 0.5*erfc((thr - lg[e]) * 16 / sqrt(2))
        #pragma unroll
        for (int e = 0; e < EE; ++e) {
            float z = (thr - lg[e]) * INV_NOISE_STD;
            float pv = 0.5f * erfcf(z * 0.70710678118654752f);
            float ws = wave_sum(pv);
            if (lane == 0) atomicAdd(&psum[e], ws);
        }

        // outputs: gates[B*E] | idx[B*K] | vals[B*K] | aux[1]
        #pragma unroll
        for (int e = 0; e < EE; ++e)
            out[b * EE + e] = (e == i1) ? v1 : ((e == i2) ? v2 : 0.0f);
        out[BB * EE + b * KK + 0] = (float)i1;
        out[BB * EE + b * KK + 1] = (float)i2;
        out[BB * EE + BB * KK + b * KK + 0] = v1;
        out[BB * EE + BB * KK + b * KK + 1] = v2;
    }
    __syncthreads();

    if (t == 0) {
        float im[EE]; float mean1 = 0.0f;
        #pragma unroll
        for (int e = 0; e < EE; ++e) { im[e] = imp[e] * complexity[e]; mean1 += im[e]; }
        mean1 *= (1.0f / EE);
        float var1 = 0.0f;
        #pragma unroll
        for (int e = 0; e < EE; ++e) { float d = im[e] - mean1; var1 += d * d; }
        var1 *= (1.0f / (EE - 1));
        float li = var1 / ((mean1 + EPSV) * (mean1 + EPSV));

        float pm[EE]; float mean2 = 0.0f;
        #pragma unroll
        for (int e = 0; e < EE; ++e) { pm[e] = psum[e] * (1.0f / BB); mean2 += pm[e]; }
        mean2 *= (1.0f / EE);
        float var2 = 0.0f;
        #pragma unroll
        for (int e = 0; e < EE; ++e) { float d = pm[e] - mean2; var2 += d * d; }
        var2 *= (1.0f / (EE - 1));
        float ll = var2 / ((mean2 + EPSV) * (mean2 + EPSV));

        out[BB * EE + 2 * BB * KK] = 0.5f * li + 0.5f * ll;
    }
}

extern "C" void kernel_launch(void* const* d_in, const int* in_sizes, int n_in,
                              void* d_out, int out_size, void* d_ws, size_t ws_size,
                              hipStream_t stream) {
    const float* x     = (const float*)d_in[0];   // [128,512,32,32]
    const float* Wg    = (const float*)d_in[1];   // [16,512]
    const float* comp  = (const float*)d_in[2];   // [16]
    const float* noise = (const float*)d_in[3];   // [128,16]
    float* out = (float*)d_out;

    float* pooled = (float*)d_ws;                 // B*C = 65536 floats

    pool_kernel<<<(BB * CC) / 8, 512, 0, stream>>>(x, pooled);
    tail_kernel<<<1, 512, 0, stream>>>(pooled, Wg, comp, noise, out);
}

// Round 5
// 357.266 us; speedup vs baseline: 7.5112x; 1.4270x over previous
//
#include <hip/hip_runtime.h>
#include <math.h>

#define BB 128
#define CC 512
#define HW 1024
#define EE 16
#define KK 2
#define INV_NOISE_STD 16.0f
#define EPSV 1e-8f

typedef float vf4 __attribute__((ext_vector_type(4)));

__device__ __forceinline__ float wave_sum(float v) {
    #pragma unroll
    for (int off = 32; off > 0; off >>= 1) v += __shfl_down(v, off, 64);
    return v;
}

// Kernel A: pooled[p] = mean over 1024 contiguous floats. One wave per (b,c).
// Nontemporal streaming reads: x is 256 MB with zero reuse.
__global__ void __launch_bounds__(256) pool_kernel(const float* __restrict__ x,
                                                   float* __restrict__ pooled) {
    int wave = (blockIdx.x * 256 + threadIdx.x) >> 6;   // global (b*C+c)
    int lane = threadIdx.x & 63;
    const vf4* p = (const vf4*)(x + (size_t)wave * HW);
    float s = 0.0f;
    #pragma unroll
    for (int j = 0; j < 4; ++j) {
        vf4 v = __builtin_nontemporal_load(&p[lane + 64 * j]);
        s += (v.x + v.y) + (v.z + v.w);
    }
    s = wave_sum(s);
    if (lane == 0) pooled[wave] = s * (1.0f / 1024.0f);
}

// Kernel B: logits[b,e] = dot(pooled[b,:], W_gate[e,:]). One block per b (128 blocks).
__global__ void __launch_bounds__(256) logits_kernel(const float* __restrict__ pooled,
                                                     const float* __restrict__ Wg,
                                                     float* __restrict__ logits) {
    __shared__ float prow[CC];
    int b = blockIdx.x;
    for (int c = threadIdx.x; c < CC; c += 256) prow[c] = pooled[b * CC + c];
    __syncthreads();
    int t = threadIdx.x;
    int e = t >> 4;      // 0..15
    int g = t & 15;      // 0..15
    float s = 0.0f;
    for (int c = g; c < CC; c += 16) s += prow[c] * Wg[e * CC + c];
    #pragma unroll
    for (int off = 8; off > 0; off >>= 1) s += __shfl_down(s, off, 16);
    if (g == 0) logits[b * EE + e] = s;
}

// Kernel C: all statistics + outputs. Single block, 128 threads (1 per batch row).
__global__ void __launch_bounds__(128) stats_kernel(const float* __restrict__ logits,
                                                    const float* __restrict__ complexity,
                                                    const float* __restrict__ noise,
                                                    float* __restrict__ out) {
    // out layout: gates[B*E] | idx[B*K] | vals[B*K] | aux[1]
    __shared__ float imp[EE];
    __shared__ float psum[EE];
    int t = threadIdx.x;
    int lane = t & 63;
    if (t < EE) { imp[t] = 0.0f; psum[t] = 0.0f; }
    __syncthreads();

    int b = t;
    float lg[EE], nlg[EE];
    #pragma unroll
    for (int e = 0; e < EE; ++e) lg[e] = logits[b * EE + e];
    #pragma unroll
    for (int e = 0; e < EE; ++e) nlg[e] = lg[e] + noise[b * EE + e];

    // softmax(logits) -> importance accumulation
    float mx = lg[0];
    #pragma unroll
    for (int e = 1; e < EE; ++e) mx = fmaxf(mx, lg[e]);
    float sm[EE]; float se = 0.0f;
    #pragma unroll
    for (int e = 0; e < EE; ++e) { sm[e] = expf(lg[e] - mx); se += sm[e]; }
    float inv_se = 1.0f / se;
    #pragma unroll
    for (int e = 0; e < EE; ++e) {
        float ws = wave_sum(sm[e] * inv_se);
        if (lane == 0) atomicAdd(&imp[e], ws);
    }

    // softmax(noisy logits) -> gating scores; top-2 (lowest-index tie-break)
    float mxn = nlg[0];
    #pragma unroll
    for (int e = 1; e < EE; ++e) mxn = fmaxf(mxn, nlg[e]);
    float gsc[EE]; float sen = 0.0f;
    #pragma unroll
    for (int e = 0; e < EE; ++e) { gsc[e] = expf(nlg[e] - mxn); sen += gsc[e]; }
    float inv_sen = 1.0f / sen;
    #pragma unroll
    for (int e = 0; e < EE; ++e) gsc[e] *= inv_sen;

    int i1 = 0;
    #pragma unroll
    for (int e = 1; e < EE; ++e) if (nlg[e] > nlg[i1]) i1 = e;
    int i2 = (i1 == 0) ? 1 : 0;
    #pragma unroll
    for (int e = 0; e < EE; ++e) if (e != i1 && e != i2 && nlg[e] > nlg[i2]) i2 = e;
    float thr = nlg[i2];
    float v1 = gsc[i1], v2 = gsc[i2];

    // load-balance probability p[e] = 0.5*erfc((thr - lg[e]) * 16 / sqrt(2))
    #pragma unroll
    for (int e = 0; e < EE; ++e) {
        float z = (thr - lg[e]) * INV_NOISE_STD;
        float p = 0.5f * erfcf(z * 0.70710678118654752f);
        float ws = wave_sum(p);
        if (lane == 0) atomicAdd(&psum[e], ws);
    }

    // dense gates + top-k outputs
    #pragma unroll
    for (int e = 0; e < EE; ++e)
        out[b * EE + e] = (e == i1) ? v1 : ((e == i2) ? v2 : 0.0f);
    out[BB * EE + b * KK + 0] = (float)i1;
    out[BB * EE + b * KK + 1] = (float)i2;
    out[BB * EE + BB * KK + b * KK + 0] = v1;
    out[BB * EE + BB * KK + b * KK + 1] = v2;

    __syncthreads();
    if (t == 0) {
        float im[EE]; float mean1 = 0.0f;
        #pragma unroll
        for (int e = 0; e < EE; ++e) { im[e] = imp[e] * complexity[e]; mean1 += im[e]; }
        mean1 *= (1.0f / EE);
        float var1 = 0.0f;
        #pragma unroll
        for (int e = 0; e < EE; ++e) { float d = im[e] - mean1; var1 += d * d; }
        var1 *= (1.0f / (EE - 1));
        float li = var1 / ((mean1 + EPSV) * (mean1 + EPSV));

        float pm[EE]; float mean2 = 0.0f;
        #pragma unroll
        for (int e = 0; e < EE; ++e) { pm[e] = psum[e] * (1.0f / BB); mean2 += pm[e]; }
        mean2 *= (1.0f / EE);
        float var2 = 0.0f;
        #pragma unroll
        for (int e = 0; e < EE; ++e) { float d = pm[e] - mean2; var2 += d * d; }
        var2 *= (1.0f / (EE - 1));
        float ll = var2 / ((mean2 + EPSV) * (mean2 + EPSV));

        out[BB * EE + 2 * BB * KK] = 0.5f * li + 0.5f * ll;
    }
}

extern "C" void kernel_launch(void* const* d_in, const int* in_sizes, int n_in,
                              void* d_out, int out_size, void* d_ws, size_t ws_size,
                              hipStream_t stream) {
    const float* x     = (const float*)d_in[0];   // [128,512,32,32]
    const float* Wg    = (const float*)d_in[1];   // [16,512]
    const float* comp  = (const float*)d_in[2];   // [16]
    const float* noise = (const float*)d_in[3];   // [128,16]
    float* out = (float*)d_out;

    float* pooled = (float*)d_ws;          // B*C = 65536 floats
    float* logits = pooled + BB * CC;      // B*E = 2048 floats

    pool_kernel<<<(BB * CC) / 4, 256, 0, stream>>>(x, pooled);
    logits_kernel<<<BB, 256, 0, stream>>>(pooled, Wg, logits);
    stats_kernel<<<1, 128, 0, stream>>>(logits, comp, noise, out);
}